// Round 1
// baseline (2293.142 us; speedup 1.0000x reference)
//
#include <hip/hip_runtime.h>
#include <math.h>

#define EDGE_SCALE 0.17677669529663687f   // 32^-0.5
#define ATT_SCALE  0.15811388300841897f   // 40^-0.5
#define LN_EPS 1e-5f

__device__ __forceinline__ float wave_max(float v) {
  #pragma unroll
  for (int o = 32; o > 0; o >>= 1) v = fmaxf(v, __shfl_xor(v, o));
  return v;
}
__device__ __forceinline__ float wave_sum(float v) {
  #pragma unroll
  for (int o = 32; o > 0; o >>= 1) v += __shfl_xor(v, o);
  return v;
}

// node[b,n,c] = x[b,c,n]
__global__ __launch_bounds__(256) void k_trans(const float* __restrict__ x, float* __restrict__ node) {
  __shared__ float tile[32][33];
  const int b = blockIdx.z;
  const int n0 = blockIdx.x * 32, c0 = blockIdx.y * 32;
  const int tx = threadIdx.x & 31, ty = threadIdx.x >> 5;  // 32 x 8
  #pragma unroll
  for (int k = 0; k < 4; ++k) {
    int c = c0 + ty + 8 * k;
    tile[ty + 8 * k][tx] = x[((size_t)b * 320 + c) * 1024 + n0 + tx];
  }
  __syncthreads();
  #pragma unroll
  for (int k = 0; k < 4; ++k) {
    int n = n0 + ty + 8 * k;
    node[((size_t)b * 1024 + n) * 320 + c0 + tx] = tile[tx][ty + 8 * k];
  }
}

// s[b,c] = sum_e (sum_a da[b,a,e]) * fw[c,e] + 16*fb[c]
__global__ __launch_bounds__(320) void k_svec(const float* __restrict__ da,
    const float* __restrict__ fw, const float* __restrict__ fb, float* __restrict__ sv) {
  __shared__ float ds[64];
  const int b = blockIdx.x, t = threadIdx.x;
  if (t < 64) {
    float a = 0.f;
    #pragma unroll
    for (int i = 0; i < 16; ++i) a += da[b * 1024 + i * 64 + t];
    ds[t] = a;
  }
  __syncthreads();
  if (t < 320) {
    float acc = 16.f * fb[t];
    #pragma unroll
    for (int e = 0; e < 64; ++e) acc = fmaf(ds[e], fw[t * 64 + e], acc);
    sv[b * 320 + t] = acc;
  }
}

// Generic tiled GEMM: out = A[2048,320] @ W[Nout,320]^T (+bias).
// mode 0: o0[row*320+col]            (plain, Nout=320)
// mode 1: col<320 -> o0[row*320+col]; else o1[(b*320+(col-320))*1024+n]   (qk split, k transposed)
// mode 2: qkv scatter: q->o0 [B,H,N,D]; k->o1, v->o2 as [B,H,D,N]
// mode 3: o0[(b*320+col)*1024+n]     (final output, [B,C,N])
__global__ __launch_bounds__(256) void k_gemm(
    const float* __restrict__ A, const float* __restrict__ W, const float* __restrict__ bias,
    float* __restrict__ o0, float* __restrict__ o1, float* __restrict__ o2, int mode) {
  __shared__ __align__(16) float As[16][68];
  __shared__ __align__(16) float Bs[16][68];
  const int t = threadIdx.x;
  const int tx = t & 15, ty = t >> 4;
  const int rt = blockIdx.x * 64, jt = blockIdx.y * 64;
  const int lr = t >> 2, lk = (t & 3) * 4;
  float acc[4][4];
  #pragma unroll
  for (int i = 0; i < 4; ++i)
    #pragma unroll
    for (int j = 0; j < 4; ++j) acc[i][j] = 0.f;
  const float* ap = A + (size_t)(rt + lr) * 320 + lk;
  const float* bp = W + (size_t)(jt + lr) * 320 + lk;
  for (int k0 = 0; k0 < 320; k0 += 16) {
    float4 a4 = *(const float4*)(ap + k0);
    float4 b4 = *(const float4*)(bp + k0);
    As[lk + 0][lr] = a4.x; As[lk + 1][lr] = a4.y; As[lk + 2][lr] = a4.z; As[lk + 3][lr] = a4.w;
    Bs[lk + 0][lr] = b4.x; Bs[lk + 1][lr] = b4.y; Bs[lk + 2][lr] = b4.z; Bs[lk + 3][lr] = b4.w;
    __syncthreads();
    #pragma unroll
    for (int kk = 0; kk < 16; ++kk) {
      float4 av = *(const float4*)(&As[kk][ty * 4]);
      float4 bv = *(const float4*)(&Bs[kk][tx * 4]);
      float aa[4] = {av.x, av.y, av.z, av.w};
      float bb[4] = {bv.x, bv.y, bv.z, bv.w};
      #pragma unroll
      for (int i = 0; i < 4; ++i)
        #pragma unroll
        for (int j = 0; j < 4; ++j) acc[i][j] = fmaf(aa[i], bb[j], acc[i][j]);
    }
    __syncthreads();
  }
  #pragma unroll
  for (int i = 0; i < 4; ++i) {
    int row = rt + ty * 4 + i;
    int b = row >> 10, n = row & 1023;
    #pragma unroll
    for (int j = 0; j < 4; ++j) {
      int col = jt + tx * 4 + j;
      float v = acc[i][j];
      if (bias) v += bias[col];
      if (mode == 0) {
        o0[(size_t)row * 320 + col] = v;
      } else if (mode == 1) {
        if (col < 320) o0[(size_t)row * 320 + col] = v;
        else o1[((size_t)b * 320 + (col - 320)) * 1024 + n] = v;
      } else if (mode == 2) {
        int part = col / 320, rem = col % 320;
        int h = rem / 40, d = rem % 40;
        if (part == 0)      o0[(((size_t)b * 8 + h) * 1024 + n) * 40 + d] = v;
        else if (part == 1) o1[(((size_t)b * 8 + h) * 40 + d) * 1024 + n] = v;
        else                o2[(((size_t)b * 8 + h) * 40 + d) * 1024 + n] = v;
      } else {
        o0[((size_t)b * 320 + col) * 1024 + n] = v;
      }
    }
  }
}

// edge = softmax(q_e @ k_e^T * EDGE_SCALE). kt is [B,C,N]. wave handles 2 rows.
__global__ __launch_bounds__(256) void k_edge(const float* __restrict__ qe,
    const float* __restrict__ kt, float* __restrict__ edge) {
  const int w = threadIdx.x >> 6, lane = threadIdx.x & 63;
  const int b = blockIdx.y;
  const int n0 = blockIdx.x * 8 + w * 2;
  const float* q0 = qe + ((size_t)b * 1024 + n0) * 320;
  const float* q1 = q0 + 320;
  const float* kb = kt + (size_t)b * 320 * 1024 + lane;
  float acc0[16], acc1[16];
  #pragma unroll
  for (int jj = 0; jj < 16; ++jj) { acc0[jj] = 0.f; acc1[jj] = 0.f; }
  for (int c = 0; c < 320; ++c) {
    float qv0 = q0[c], qv1 = q1[c];
    const float* kp = kb + (size_t)c * 1024;
    #pragma unroll
    for (int jj = 0; jj < 16; ++jj) {
      float kv = kp[jj * 64];
      acc0[jj] = fmaf(qv0, kv, acc0[jj]);
      acc1[jj] = fmaf(qv1, kv, acc1[jj]);
    }
  }
  float* e0 = edge + ((size_t)b * 1024 + n0) * 1024 + lane;
  {
    float mx = -3.4e38f;
    #pragma unroll
    for (int jj = 0; jj < 16; ++jj) { acc0[jj] *= EDGE_SCALE; mx = fmaxf(mx, acc0[jj]); }
    mx = wave_max(mx);
    float s = 0.f;
    #pragma unroll
    for (int jj = 0; jj < 16; ++jj) { acc0[jj] = __expf(acc0[jj] - mx); s += acc0[jj]; }
    s = wave_sum(s);
    float inv = 1.f / s;
    #pragma unroll
    for (int jj = 0; jj < 16; ++jj) e0[jj * 64] = acc0[jj] * inv;
  }
  {
    float mx = -3.4e38f;
    #pragma unroll
    for (int jj = 0; jj < 16; ++jj) { acc1[jj] *= EDGE_SCALE; mx = fmaxf(mx, acc1[jj]); }
    mx = wave_max(mx);
    float s = 0.f;
    #pragma unroll
    for (int jj = 0; jj < 16; ++jj) { acc1[jj] = __expf(acc1[jj] - mx); s += acc1[jj]; }
    s = wave_sum(s);
    float inv = 1.f / s;
    float* e1 = e0 + 1024;
    #pragma unroll
    for (int jj = 0; jj < 16; ++jj) e1[jj * 64] = acc1[jj] * inv;
  }
}

// y = LN(diag*LN(node)*s + LN(node)) per row; wave = 1 row.
__global__ __launch_bounds__(256) void k_ln(const float* __restrict__ node,
    const float* __restrict__ edge, const float* __restrict__ sv,
    const float* __restrict__ g1, const float* __restrict__ b1,
    const float* __restrict__ g2, const float* __restrict__ b2,
    float* __restrict__ y) {
  const int w = threadIdx.x >> 6, lane = threadIdx.x & 63;
  const int row = blockIdx.x * 4 + w;
  const int b = row >> 10, n = row & 1023;
  const float* xr = node + (size_t)row * 320;
  float x[5];
  #pragma unroll
  for (int i = 0; i < 5; ++i) x[i] = xr[lane + 64 * i];
  float s = x[0] + x[1] + x[2] + x[3] + x[4];
  float mean = wave_sum(s) * (1.f / 320.f);
  float v = 0.f;
  #pragma unroll
  for (int i = 0; i < 5; ++i) { float d = x[i] - mean; v += d * d; }
  float rstd = rsqrtf(wave_sum(v) * (1.f / 320.f) + LN_EPS);
  float diag = edge[(size_t)row * 1024 + n];
  float n2[5];
  #pragma unroll
  for (int i = 0; i < 5; ++i) {
    int c = lane + 64 * i;
    float nt = (x[i] - mean) * rstd * g1[c] + b1[c];
    n2[i] = diag * nt * sv[b * 320 + c] + nt;
  }
  s = n2[0] + n2[1] + n2[2] + n2[3] + n2[4];
  float mean2 = wave_sum(s) * (1.f / 320.f);
  v = 0.f;
  #pragma unroll
  for (int i = 0; i < 5; ++i) { float d = n2[i] - mean2; v += d * d; }
  float rstd2 = rsqrtf(wave_sum(v) * (1.f / 320.f) + LN_EPS);
  float* yr = y + (size_t)row * 320;
  #pragma unroll
  for (int i = 0; i < 5; ++i) {
    int c = lane + 64 * i;
    yr[c] = (n2[i] - mean2) * rstd2 * g2[c] + b2[c];
  }
}

// Fused attention + edge update + wsum. Block = 8 rows (8 waves, wave = 1 row).
// q [B,H,N,D]; kt,vt [B,H,D,N]; edge in/out [B,N,N]; att out [B,N,C] (wsum folded in).
__global__ __launch_bounds__(512) void k_attn(
    const float* __restrict__ q, const float* __restrict__ kt, const float* __restrict__ vt,
    float* __restrict__ edge, float* __restrict__ att,
    const float* __restrict__ ew, const float* __restrict__ eb,
    const float* __restrict__ rw, const float* __restrict__ rb) {
  __shared__ float pr[8][64][21];      // per-wave transpose scratch
  __shared__ float nodebuf[8][320];
  const int w = threadIdx.x >> 6, lane = threadIdx.x & 63;
  const int b = blockIdx.y;
  const int n = blockIdx.x * 8 + w;
  const int row = b * 1024 + n;
  for (int i = threadIdx.x; i < 8 * 320; i += 512) (&nodebuf[0][0])[i] = 0.f;
  __syncthreads();
  float* erow = edge + (size_t)row * 1024 + lane;
  float ebias[16], treg[16];
  #pragma unroll
  for (int jj = 0; jj < 16; ++jj) ebias[jj] = erow[jj * 64];
  const float rbv = rb[0];
  #pragma unroll
  for (int jj = 0; jj < 16; ++jj) treg[jj] = rbv;
  #pragma unroll 1
  for (int h = 0; h < 8; ++h) {
    const float* qrow = q + (((size_t)b * 8 + h) * 1024 + n) * 40;
    const float* kb = kt + ((size_t)b * 8 + h) * 40 * 1024 + lane;
    const float* vb = vt + ((size_t)b * 8 + h) * 40 * 1024 + lane;
    float acc[16];
    #pragma unroll
    for (int jj = 0; jj < 16; ++jj) acc[jj] = 0.f;
    for (int d = 0; d < 40; ++d) {
      float qv = qrow[d];
      const float* kp = kb + d * 1024;
      #pragma unroll
      for (int jj = 0; jj < 16; ++jj) acc[jj] = fmaf(qv, kp[jj * 64], acc[jj]);
    }
    const float ewh = ew[h], ebh = eb[h], rwh = rw[h];
    float mx = -3.4e38f;
    #pragma unroll
    for (int jj = 0; jj < 16; ++jj) {
      acc[jj] = fmaf(acc[jj], ATT_SCALE, fmaf(ebias[jj], ewh, ebh));
      mx = fmaxf(mx, acc[jj]);
    }
    mx = wave_max(mx);
    float av[16], ssum = 0.f;
    #pragma unroll
    for (int jj = 0; jj < 16; ++jj) { av[jj] = __expf(acc[jj] - mx); ssum += av[jj]; }
    ssum = wave_sum(ssum);
    const float inv = 1.f / ssum;
    #pragma unroll
    for (int jj = 0; jj < 16; ++jj) {
      av[jj] *= inv;
      treg[jj] += (av[jj] + acc[jj]) * rwh;
    }
    // a @ v : per-lane partials over this lane's 16 m-columns
    float p[40];
    #pragma unroll
    for (int d = 0; d < 40; ++d) {
      const float* vp = vb + d * 1024;
      float sacc = 0.f;
      #pragma unroll
      for (int jj = 0; jj < 16; ++jj) sacc = fmaf(av[jj], vp[jj * 64], sacc);
      p[d] = sacc;
    }
    // cross-lane reduce via LDS transpose (2 passes of 20 d's)
    #pragma unroll
    for (int pass = 0; pass < 2; ++pass) {
      __syncthreads();
      #pragma unroll
      for (int d = 0; d < 20; ++d) pr[w][lane][d] = p[pass * 20 + d];
      __syncthreads();
      if (lane < 20) {
        float csum = 0.f;
        #pragma unroll
        for (int l = 0; l < 64; ++l) csum += pr[w][l][lane];
        nodebuf[w][h * 40 + pass * 20 + lane] += csum;
      }
    }
  }
  // ws = softmax(t); wsum = sum(ws*t)
  float mx2 = -3.4e38f;
  #pragma unroll
  for (int jj = 0; jj < 16; ++jj) mx2 = fmaxf(mx2, treg[jj]);
  mx2 = wave_max(mx2);
  float s2 = 0.f, num = 0.f;
  #pragma unroll
  for (int jj = 0; jj < 16; ++jj) {
    float e = __expf(treg[jj] - mx2);
    s2 += e; num += e * treg[jj];
  }
  s2 = wave_sum(s2); num = wave_sum(num);
  const float wsum = num / s2;
  // edge += edge_new
  #pragma unroll
  for (int jj = 0; jj < 16; ++jj) erow[jj * 64] = ebias[jj] + treg[jj];
  __syncthreads();
  float* arow = att + (size_t)row * 320;
  #pragma unroll
  for (int i = 0; i < 5; ++i) {
    int c = lane + 64 * i;
    arow[c] = nodebuf[w][c] + wsum;
  }
}

extern "C" void kernel_launch(void* const* d_in, const int* in_sizes, int n_in,
                              void* d_out, int out_size, void* d_ws, size_t ws_size,
                              hipStream_t stream) {
  const float* x      = (const float*)d_in[0];
  const float* da     = (const float*)d_in[1];
  const float* qk_w   = (const float*)d_in[2];
  const float* fcp_w  = (const float*)d_in[3];
  const float* fcp_b  = (const float*)d_in[4];
  const float* ln1_g  = (const float*)d_in[5];
  const float* ln1_b  = (const float*)d_in[6];
  const float* gln_g  = (const float*)d_in[7];
  const float* gln_b  = (const float*)d_in[8];
  const float* qkv_w  = (const float*)d_in[9];
  const float* qkv_b  = (const float*)d_in[10];
  const float* proj_w = (const float*)d_in[11];
  const float* proj_b = (const float*)d_in[12];
  const float* exp_w  = (const float*)d_in[13];
  const float* exp_b  = (const float*)d_in[14];
  const float* red_w  = (const float*)d_in[15];
  const float* red_b  = (const float*)d_in[16];
  float* ws = (float*)d_ws;
  const size_t SZ = (size_t)2 * 1024 * 320;  // 655360
  float* node = ws;
  float* y    = ws + SZ;
  float* qb   = ws + 2 * SZ;
  float* ktb  = ws + 3 * SZ;
  float* vtb  = ws + 4 * SZ;
  float* attb = ws + 5 * SZ;
  float* edge = ws + 6 * SZ;                         // 2*1024*1024
  float* svec = ws + 6 * SZ + (size_t)2 * 1024 * 1024;
  float* out  = (float*)d_out;

  hipLaunchKernelGGL(k_trans, dim3(32, 10, 2), dim3(256), 0, stream, x, node);
  hipLaunchKernelGGL(k_svec, dim3(2), dim3(320), 0, stream, da, fcp_w, fcp_b, svec);
  hipLaunchKernelGGL(k_gemm, dim3(32, 10), dim3(256), 0, stream,
                     node, qk_w, (const float*)nullptr, qb, ktb, (float*)nullptr, 1);
  hipLaunchKernelGGL(k_edge, dim3(128, 2), dim3(256), 0, stream, qb, ktb, edge);
  for (int l = 0; l < 2; ++l) {
    hipLaunchKernelGGL(k_ln, dim3(512), dim3(256), 0, stream, node, edge, svec,
                       ln1_g + l * 320, ln1_b + l * 320, gln_g + l * 320, gln_b + l * 320, y);
    hipLaunchKernelGGL(k_gemm, dim3(32, 15), dim3(256), 0, stream,
                       y, qkv_w + (size_t)l * 960 * 320, qkv_b + l * 960, qb, ktb, vtb, 2);
    hipLaunchKernelGGL(k_attn, dim3(128, 2), dim3(512), 0, stream, qb, ktb, vtb, edge, attb,
                       exp_w + l * 8, exp_b + l * 8, red_w + l * 8, red_b + l);
    if (l == 0)
      hipLaunchKernelGGL(k_gemm, dim3(32, 5), dim3(256), 0, stream,
                         attb, proj_w, proj_b, node, (float*)nullptr, (float*)nullptr, 0);
    else
      hipLaunchKernelGGL(k_gemm, dim3(32, 5), dim3(256), 0, stream,
                         attb, proj_w + (size_t)320 * 320, proj_b + 320, out,
                         (float*)nullptr, (float*)nullptr, 3);
  }
}

// Round 2
// 876.762 us; speedup vs baseline: 2.6155x; 2.6155x over previous
//
#include <hip/hip_runtime.h>
#include <math.h>

#define EDGE_SCALE 0.17677669529663687f   // 32^-0.5
#define ATT_SCALE  0.15811388300841897f   // 40^-0.5
#define LN_EPS 1e-5f

__device__ __forceinline__ float wave_max(float v) {
  #pragma unroll
  for (int o = 32; o > 0; o >>= 1) v = fmaxf(v, __shfl_xor(v, o));
  return v;
}
__device__ __forceinline__ float wave_sum(float v) {
  #pragma unroll
  for (int o = 32; o > 0; o >>= 1) v += __shfl_xor(v, o);
  return v;
}

// node[b,n,c] = x[b,c,n]
__global__ __launch_bounds__(256) void k_trans(const float* __restrict__ x, float* __restrict__ node) {
  __shared__ float tile[32][33];
  const int b = blockIdx.z;
  const int n0 = blockIdx.x * 32, c0 = blockIdx.y * 32;
  const int tx = threadIdx.x & 31, ty = threadIdx.x >> 5;  // 32 x 8
  #pragma unroll
  for (int k = 0; k < 4; ++k) {
    int c = c0 + ty + 8 * k;
    tile[ty + 8 * k][tx] = x[((size_t)b * 320 + c) * 1024 + n0 + tx];
  }
  __syncthreads();
  #pragma unroll
  for (int k = 0; k < 4; ++k) {
    int n = n0 + ty + 8 * k;
    node[((size_t)b * 1024 + n) * 320 + c0 + tx] = tile[tx][ty + 8 * k];
  }
}

// s[b,c] = sum_e (sum_a da[b,a,e]) * fw[c,e] + 16*fb[c]
__global__ __launch_bounds__(320) void k_svec(const float* __restrict__ da,
    const float* __restrict__ fw, const float* __restrict__ fb, float* __restrict__ sv) {
  __shared__ float ds[64];
  const int b = blockIdx.x, t = threadIdx.x;
  if (t < 64) {
    float a = 0.f;
    #pragma unroll
    for (int i = 0; i < 16; ++i) a += da[b * 1024 + i * 64 + t];
    ds[t] = a;
  }
  __syncthreads();
  if (t < 320) {
    float acc = 16.f * fb[t];
    #pragma unroll
    for (int e = 0; e < 64; ++e) acc = fmaf(ds[e], fw[t * 64 + e], acc);
    sv[b * 320 + t] = acc;
  }
}

// Generic tiled GEMM: out = A[2048,320] @ W[Nout,320]^T (+bias).
__global__ __launch_bounds__(256) void k_gemm(
    const float* __restrict__ A, const float* __restrict__ W, const float* __restrict__ bias,
    float* __restrict__ o0, float* __restrict__ o1, float* __restrict__ o2, int mode) {
  __shared__ __align__(16) float As[16][68];
  __shared__ __align__(16) float Bs[16][68];
  const int t = threadIdx.x;
  const int tx = t & 15, ty = t >> 4;
  const int rt = blockIdx.x * 64, jt = blockIdx.y * 64;
  const int lr = t >> 2, lk = (t & 3) * 4;
  float acc[4][4];
  #pragma unroll
  for (int i = 0; i < 4; ++i)
    #pragma unroll
    for (int j = 0; j < 4; ++j) acc[i][j] = 0.f;
  const float* ap = A + (size_t)(rt + lr) * 320 + lk;
  const float* bp = W + (size_t)(jt + lr) * 320 + lk;
  for (int k0 = 0; k0 < 320; k0 += 16) {
    float4 a4 = *(const float4*)(ap + k0);
    float4 b4 = *(const float4*)(bp + k0);
    As[lk + 0][lr] = a4.x; As[lk + 1][lr] = a4.y; As[lk + 2][lr] = a4.z; As[lk + 3][lr] = a4.w;
    Bs[lk + 0][lr] = b4.x; Bs[lk + 1][lr] = b4.y; Bs[lk + 2][lr] = b4.z; Bs[lk + 3][lr] = b4.w;
    __syncthreads();
    #pragma unroll
    for (int kk = 0; kk < 16; ++kk) {
      float4 av = *(const float4*)(&As[kk][ty * 4]);
      float4 bv = *(const float4*)(&Bs[kk][tx * 4]);
      float aa[4] = {av.x, av.y, av.z, av.w};
      float bb[4] = {bv.x, bv.y, bv.z, bv.w};
      #pragma unroll
      for (int i = 0; i < 4; ++i)
        #pragma unroll
        for (int j = 0; j < 4; ++j) acc[i][j] = fmaf(aa[i], bb[j], acc[i][j]);
    }
    __syncthreads();
  }
  #pragma unroll
  for (int i = 0; i < 4; ++i) {
    int row = rt + ty * 4 + i;
    int b = row >> 10, n = row & 1023;
    #pragma unroll
    for (int j = 0; j < 4; ++j) {
      int col = jt + tx * 4 + j;
      float v = acc[i][j];
      if (bias) v += bias[col];
      if (mode == 0) {
        o0[(size_t)row * 320 + col] = v;
      } else if (mode == 1) {
        if (col < 320) o0[(size_t)row * 320 + col] = v;
        else o1[((size_t)b * 320 + (col - 320)) * 1024 + n] = v;
      } else if (mode == 2) {
        int part = col / 320, rem = col % 320;
        int h = rem / 40, d = rem % 40;
        if (part == 0)      o0[(((size_t)b * 8 + h) * 1024 + n) * 40 + d] = v;
        else if (part == 1) o1[(((size_t)b * 8 + h) * 40 + d) * 1024 + n] = v;
        else                o2[(((size_t)b * 8 + h) * 40 + d) * 1024 + n] = v;
      } else {
        o0[((size_t)b * 320 + col) * 1024 + n] = v;
      }
    }
  }
}

// edge = softmax(q_e @ k_e^T * EDGE_SCALE). kt is [B,C,N].
// Block = 256 thr (4 waves); wave = 2 rows; K chunks staged in LDS.
// Lane holds cols jj*128 + 2*lane + {0,1}, jj in [0,8).
__global__ __launch_bounds__(256, 2) void k_edge(const float* __restrict__ qe,
    const float* __restrict__ kt, float* __restrict__ edge) {
  __shared__ float kbuf[8][1024];
  const int t = threadIdx.x, w = t >> 6, lane = t & 63;
  const int b = blockIdx.y;
  const int n0 = blockIdx.x * 8 + w * 2;
  const float* q0 = qe + ((size_t)b * 1024 + n0) * 320;
  const float* q1 = q0 + 320;
  const float* kbase = kt + (size_t)b * 320 * 1024;
  float2 acc0[8], acc1[8];
  #pragma unroll
  for (int j = 0; j < 8; ++j) { acc0[j] = make_float2(0.f, 0.f); acc1[j] = make_float2(0.f, 0.f); }
  #pragma unroll 1
  for (int c = 0; c < 40; ++c) {
    __syncthreads();
    const float4* src = (const float4*)(kbase + (size_t)c * 8192);
    #pragma unroll
    for (int i = 0; i < 8; ++i) ((float4*)kbuf)[i * 256 + t] = src[i * 256 + t];
    __syncthreads();
    #pragma unroll
    for (int d = 0; d < 8; ++d) {
      float qv0 = q0[c * 8 + d], qv1 = q1[c * 8 + d];
      const float2* kr = (const float2*)(&kbuf[d][0]) + lane;
      #pragma unroll
      for (int jj = 0; jj < 8; ++jj) {
        float2 kv = kr[jj * 64];
        acc0[jj].x = fmaf(qv0, kv.x, acc0[jj].x);
        acc0[jj].y = fmaf(qv0, kv.y, acc0[jj].y);
        acc1[jj].x = fmaf(qv1, kv.x, acc1[jj].x);
        acc1[jj].y = fmaf(qv1, kv.y, acc1[jj].y);
      }
    }
  }
  float2* e0 = (float2*)(edge + ((size_t)b * 1024 + n0) * 1024) + lane;
  float2* e1 = e0 + 512;
  {
    float mx = -3.4e38f;
    #pragma unroll
    for (int jj = 0; jj < 8; ++jj) {
      acc0[jj].x *= EDGE_SCALE; acc0[jj].y *= EDGE_SCALE;
      mx = fmaxf(mx, fmaxf(acc0[jj].x, acc0[jj].y));
    }
    mx = wave_max(mx);
    float s = 0.f;
    #pragma unroll
    for (int jj = 0; jj < 8; ++jj) {
      acc0[jj].x = __expf(acc0[jj].x - mx); acc0[jj].y = __expf(acc0[jj].y - mx);
      s += acc0[jj].x + acc0[jj].y;
    }
    s = wave_sum(s);
    float inv = 1.f / s;
    #pragma unroll
    for (int jj = 0; jj < 8; ++jj)
      e0[jj * 64] = make_float2(acc0[jj].x * inv, acc0[jj].y * inv);
  }
  {
    float mx = -3.4e38f;
    #pragma unroll
    for (int jj = 0; jj < 8; ++jj) {
      acc1[jj].x *= EDGE_SCALE; acc1[jj].y *= EDGE_SCALE;
      mx = fmaxf(mx, fmaxf(acc1[jj].x, acc1[jj].y));
    }
    mx = wave_max(mx);
    float s = 0.f;
    #pragma unroll
    for (int jj = 0; jj < 8; ++jj) {
      acc1[jj].x = __expf(acc1[jj].x - mx); acc1[jj].y = __expf(acc1[jj].y - mx);
      s += acc1[jj].x + acc1[jj].y;
    }
    s = wave_sum(s);
    float inv = 1.f / s;
    #pragma unroll
    for (int jj = 0; jj < 8; ++jj)
      e1[jj * 64] = make_float2(acc1[jj].x * inv, acc1[jj].y * inv);
  }
}

// y = LN(diag*LN(node)*s + LN(node)) per row; wave = 1 row.
__global__ __launch_bounds__(256) void k_ln(const float* __restrict__ node,
    const float* __restrict__ edge, const float* __restrict__ sv,
    const float* __restrict__ g1, const float* __restrict__ b1,
    const float* __restrict__ g2, const float* __restrict__ b2,
    float* __restrict__ y) {
  const int w = threadIdx.x >> 6, lane = threadIdx.x & 63;
  const int row = blockIdx.x * 4 + w;
  const int b = row >> 10, n = row & 1023;
  const float* xr = node + (size_t)row * 320;
  float x[5];
  #pragma unroll
  for (int i = 0; i < 5; ++i) x[i] = xr[lane + 64 * i];
  float s = x[0] + x[1] + x[2] + x[3] + x[4];
  float mean = wave_sum(s) * (1.f / 320.f);
  float v = 0.f;
  #pragma unroll
  for (int i = 0; i < 5; ++i) { float d = x[i] - mean; v += d * d; }
  float rstd = rsqrtf(wave_sum(v) * (1.f / 320.f) + LN_EPS);
  float diag = edge[(size_t)row * 1024 + n];
  float n2[5];
  #pragma unroll
  for (int i = 0; i < 5; ++i) {
    int c = lane + 64 * i;
    float nt = (x[i] - mean) * rstd * g1[c] + b1[c];
    n2[i] = diag * nt * sv[b * 320 + c] + nt;
  }
  s = n2[0] + n2[1] + n2[2] + n2[3] + n2[4];
  float mean2 = wave_sum(s) * (1.f / 320.f);
  v = 0.f;
  #pragma unroll
  for (int i = 0; i < 5; ++i) { float d = n2[i] - mean2; v += d * d; }
  float rstd2 = rsqrtf(wave_sum(v) * (1.f / 320.f) + LN_EPS);
  float* yr = y + (size_t)row * 320;
  #pragma unroll
  for (int i = 0; i < 5; ++i) {
    int c = lane + 64 * i;
    yr[c] = (n2[i] - mean2) * rstd2 * g2[c] + b2[c];
  }
}

// Fused attention + edge update + wsum.
// Block = 256 thr (4 waves); wave = 2 rows (8 rows/block). K/V chunks in LDS.
// q [B,H,N,D]; kt,vt [B,H,D,N]; edge in/out [B,N,N]; att out [B,N,C] (wsum folded).
// Lane holds cols jj*128 + 2*lane + {0,1}.
__global__ __launch_bounds__(256, 2) void k_attn(
    const float* __restrict__ q, const float* __restrict__ kt, const float* __restrict__ vt,
    float* __restrict__ edge, float* __restrict__ att,
    const float* __restrict__ ew, const float* __restrict__ eb,
    const float* __restrict__ rw, const float* __restrict__ rb) {
  __shared__ float kvbuf[8][1024];     // 32 KB chunk (K or V)
  __shared__ float nodebuf[8][320];    // 10 KB per-row outputs
  const int t = threadIdx.x, w = t >> 6, lane = t & 63;
  const int b = blockIdx.y;
  const int n0 = blockIdx.x * 8 + w * 2;
  const size_t row0 = (size_t)b * 1024 + n0;
  float2* erow0 = (float2*)(edge + row0 * 1024) + lane;
  float2* erow1 = erow0 + 512;
  const float rbv = rb[0];
  float2 treg0[8], treg1[8];
  #pragma unroll
  for (int j = 0; j < 8; ++j) { treg0[j] = make_float2(rbv, rbv); treg1[j] = make_float2(rbv, rbv); }
  float o0 = 0.f, o1 = 0.f;            // AV result; lane L holds dim d=L (L<40)
  #pragma unroll 1
  for (int h = 0; h < 8; ++h) {
    const float* qrow0 = q + (((size_t)b * 8 + h) * 1024 + n0) * 40;
    const float* qrow1 = qrow0 + 40;
    const float* kbase = kt + ((size_t)b * 8 + h) * 40 * 1024;
    const float* vbase = vt + ((size_t)b * 8 + h) * 40 * 1024;
    float2 acc0[8], acc1[8];
    #pragma unroll
    for (int j = 0; j < 8; ++j) { acc0[j] = make_float2(0.f, 0.f); acc1[j] = make_float2(0.f, 0.f); }
    // ---- scores: Q @ K^T over d-chunks of 8 ----
    #pragma unroll 1
    for (int c = 0; c < 5; ++c) {
      __syncthreads();
      const float4* src = (const float4*)(kbase + (size_t)c * 8192);
      #pragma unroll
      for (int i = 0; i < 8; ++i) ((float4*)kvbuf)[i * 256 + t] = src[i * 256 + t];
      __syncthreads();
      #pragma unroll
      for (int d = 0; d < 8; ++d) {
        float qv0 = qrow0[c * 8 + d], qv1 = qrow1[c * 8 + d];
        const float2* kr = (const float2*)(&kvbuf[d][0]) + lane;
        #pragma unroll
        for (int jj = 0; jj < 8; ++jj) {
          float2 kv = kr[jj * 64];
          acc0[jj].x = fmaf(qv0, kv.x, acc0[jj].x);
          acc0[jj].y = fmaf(qv0, kv.y, acc0[jj].y);
          acc1[jj].x = fmaf(qv1, kv.x, acc1[jj].x);
          acc1[jj].y = fmaf(qv1, kv.y, acc1[jj].y);
        }
      }
    }
    // ---- bias + softmax + edge_new accumulation ----
    const float ewh = ew[h], ebh = eb[h], rwh = rw[h];
    float mx0 = -3.4e38f, mx1 = -3.4e38f;
    #pragma unroll
    for (int jj = 0; jj < 8; ++jj) {
      float2 e2 = erow0[jj * 64];
      acc0[jj].x = fmaf(acc0[jj].x, ATT_SCALE, fmaf(e2.x, ewh, ebh));
      acc0[jj].y = fmaf(acc0[jj].y, ATT_SCALE, fmaf(e2.y, ewh, ebh));
      treg0[jj].x = fmaf(acc0[jj].x, rwh, treg0[jj].x);
      treg0[jj].y = fmaf(acc0[jj].y, rwh, treg0[jj].y);
      mx0 = fmaxf(mx0, fmaxf(acc0[jj].x, acc0[jj].y));
      e2 = erow1[jj * 64];
      acc1[jj].x = fmaf(acc1[jj].x, ATT_SCALE, fmaf(e2.x, ewh, ebh));
      acc1[jj].y = fmaf(acc1[jj].y, ATT_SCALE, fmaf(e2.y, ewh, ebh));
      treg1[jj].x = fmaf(acc1[jj].x, rwh, treg1[jj].x);
      treg1[jj].y = fmaf(acc1[jj].y, rwh, treg1[jj].y);
      mx1 = fmaxf(mx1, fmaxf(acc1[jj].x, acc1[jj].y));
    }
    mx0 = wave_max(mx0); mx1 = wave_max(mx1);
    float s0 = 0.f, s1 = 0.f;
    #pragma unroll
    for (int jj = 0; jj < 8; ++jj) {
      acc0[jj].x = __expf(acc0[jj].x - mx0); acc0[jj].y = __expf(acc0[jj].y - mx0);
      s0 += acc0[jj].x + acc0[jj].y;
      acc1[jj].x = __expf(acc1[jj].x - mx1); acc1[jj].y = __expf(acc1[jj].y - mx1);
      s1 += acc1[jj].x + acc1[jj].y;
    }
    s0 = wave_sum(s0); s1 = wave_sum(s1);
    const float inv0 = 1.f / s0, inv1 = 1.f / s1;
    const float ir0 = inv0 * rwh, ir1 = inv1 * rwh;
    #pragma unroll
    for (int jj = 0; jj < 8; ++jj) {
      treg0[jj].x = fmaf(acc0[jj].x, ir0, treg0[jj].x);
      treg0[jj].y = fmaf(acc0[jj].y, ir0, treg0[jj].y);
      acc0[jj].x *= inv0; acc0[jj].y *= inv0;
      treg1[jj].x = fmaf(acc1[jj].x, ir1, treg1[jj].x);
      treg1[jj].y = fmaf(acc1[jj].y, ir1, treg1[jj].y);
      acc1[jj].x *= inv1; acc1[jj].y *= inv1;
    }
    // ---- A @ V over d-chunks of 8; butterfly reduce per d ----
    #pragma unroll 1
    for (int c = 0; c < 5; ++c) {
      __syncthreads();
      const float4* src = (const float4*)(vbase + (size_t)c * 8192);
      #pragma unroll
      for (int i = 0; i < 8; ++i) ((float4*)kvbuf)[i * 256 + t] = src[i * 256 + t];
      __syncthreads();
      #pragma unroll
      for (int d = 0; d < 8; ++d) {
        const float2* vr = (const float2*)(&kvbuf[d][0]) + lane;
        float p0 = 0.f, p1 = 0.f;
        #pragma unroll
        for (int jj = 0; jj < 8; ++jj) {
          float2 vv = vr[jj * 64];
          p0 = fmaf(acc0[jj].x, vv.x, p0); p0 = fmaf(acc0[jj].y, vv.y, p0);
          p1 = fmaf(acc1[jj].x, vv.x, p1); p1 = fmaf(acc1[jj].y, vv.y, p1);
        }
        #pragma unroll
        for (int o = 32; o > 0; o >>= 1) { p0 += __shfl_xor(p0, o); p1 += __shfl_xor(p1, o); }
        if (lane == c * 8 + d) { o0 = p0; o1 = p1; }
      }
    }
    if (lane < 40) {
      nodebuf[w * 2][h * 40 + lane] = o0;
      nodebuf[w * 2 + 1][h * 40 + lane] = o1;
    }
  }
  // ---- ws = softmax(edge_new); wsum = sum(ws*edge_new) per row ----
  float wsum0, wsum1;
  {
    float mx = -3.4e38f;
    #pragma unroll
    for (int jj = 0; jj < 8; ++jj) mx = fmaxf(mx, fmaxf(treg0[jj].x, treg0[jj].y));
    mx = wave_max(mx);
    float s = 0.f, num = 0.f;
    #pragma unroll
    for (int jj = 0; jj < 8; ++jj) {
      float e = __expf(treg0[jj].x - mx); s += e; num += e * treg0[jj].x;
      e = __expf(treg0[jj].y - mx); s += e; num += e * treg0[jj].y;
    }
    s = wave_sum(s); num = wave_sum(num);
    wsum0 = num / s;
  }
  {
    float mx = -3.4e38f;
    #pragma unroll
    for (int jj = 0; jj < 8; ++jj) mx = fmaxf(mx, fmaxf(treg1[jj].x, treg1[jj].y));
    mx = wave_max(mx);
    float s = 0.f, num = 0.f;
    #pragma unroll
    for (int jj = 0; jj < 8; ++jj) {
      float e = __expf(treg1[jj].x - mx); s += e; num += e * treg1[jj].x;
      e = __expf(treg1[jj].y - mx); s += e; num += e * treg1[jj].y;
    }
    s = wave_sum(s); num = wave_sum(num);
    wsum1 = num / s;
  }
  // ---- edge += edge_new ----
  #pragma unroll
  for (int jj = 0; jj < 8; ++jj) {
    float2 e2 = erow0[jj * 64];
    erow0[jj * 64] = make_float2(e2.x + treg0[jj].x, e2.y + treg0[jj].y);
    e2 = erow1[jj * 64];
    erow1[jj * 64] = make_float2(e2.x + treg1[jj].x, e2.y + treg1[jj].y);
  }
  // ---- att = AV + wsum ----
  float* arow0 = att + row0 * 320;
  float* arow1 = arow0 + 320;
  #pragma unroll
  for (int i = 0; i < 5; ++i) {
    int c = lane + 64 * i;
    arow0[c] = nodebuf[w * 2][c] + wsum0;
    arow1[c] = nodebuf[w * 2 + 1][c] + wsum1;
  }
}

extern "C" void kernel_launch(void* const* d_in, const int* in_sizes, int n_in,
                              void* d_out, int out_size, void* d_ws, size_t ws_size,
                              hipStream_t stream) {
  const float* x      = (const float*)d_in[0];
  const float* da     = (const float*)d_in[1];
  const float* qk_w   = (const float*)d_in[2];
  const float* fcp_w  = (const float*)d_in[3];
  const float* fcp_b  = (const float*)d_in[4];
  const float* ln1_g  = (const float*)d_in[5];
  const float* ln1_b  = (const float*)d_in[6];
  const float* gln_g  = (const float*)d_in[7];
  const float* gln_b  = (const float*)d_in[8];
  const float* qkv_w  = (const float*)d_in[9];
  const float* qkv_b  = (const float*)d_in[10];
  const float* proj_w = (const float*)d_in[11];
  const float* proj_b = (const float*)d_in[12];
  const float* exp_w  = (const float*)d_in[13];
  const float* exp_b  = (const float*)d_in[14];
  const float* red_w  = (const float*)d_in[15];
  const float* red_b  = (const float*)d_in[16];
  float* ws = (float*)d_ws;
  const size_t SZ = (size_t)2 * 1024 * 320;  // 655360
  float* node = ws;
  float* y    = ws + SZ;
  float* qb   = ws + 2 * SZ;
  float* ktb  = ws + 3 * SZ;
  float* vtb  = ws + 4 * SZ;
  float* attb = ws + 5 * SZ;
  float* edge = ws + 6 * SZ;                         // 2*1024*1024
  float* svec = ws + 6 * SZ + (size_t)2 * 1024 * 1024;
  float* out  = (float*)d_out;

  hipLaunchKernelGGL(k_trans, dim3(32, 10, 2), dim3(256), 0, stream, x, node);
  hipLaunchKernelGGL(k_svec, dim3(2), dim3(320), 0, stream, da, fcp_w, fcp_b, svec);
  hipLaunchKernelGGL(k_gemm, dim3(32, 10), dim3(256), 0, stream,
                     node, qk_w, (const float*)nullptr, qb, ktb, (float*)nullptr, 1);
  hipLaunchKernelGGL(k_edge, dim3(128, 2), dim3(256), 0, stream, qb, ktb, edge);
  for (int l = 0; l < 2; ++l) {
    hipLaunchKernelGGL(k_ln, dim3(512), dim3(256), 0, stream, node, edge, svec,
                       ln1_g + l * 320, ln1_b + l * 320, gln_g + l * 320, gln_b + l * 320, y);
    hipLaunchKernelGGL(k_gemm, dim3(32, 15), dim3(256), 0, stream,
                       y, qkv_w + (size_t)l * 960 * 320, qkv_b + l * 960, qb, ktb, vtb, 2);
    hipLaunchKernelGGL(k_attn, dim3(128, 2), dim3(256), 0, stream, qb, ktb, vtb, edge, attb,
                       exp_w + l * 8, exp_b + l * 8, red_w + l * 8, red_b + l);
    if (l == 0)
      hipLaunchKernelGGL(k_gemm, dim3(32, 5), dim3(256), 0, stream,
                         attb, proj_w, proj_b, node, (float*)nullptr, (float*)nullptr, 0);
    else
      hipLaunchKernelGGL(k_gemm, dim3(32, 5), dim3(256), 0, stream,
                         attb, proj_w + (size_t)320 * 320, proj_b + 320, out,
                         (float*)nullptr, (float*)nullptr, 3);
  }
}

// Round 3
// 300.892 us; speedup vs baseline: 7.6212x; 2.9139x over previous
//
#include <hip/hip_runtime.h>
#include <math.h>

#define EDGE_SCALE 0.17677669529663687f   // 32^-0.5
#define ATT_SCALE  0.15811388300841897f   // 40^-0.5
#define LN_EPS 1e-5f

typedef __attribute__((ext_vector_type(8))) short bf8;
typedef __attribute__((ext_vector_type(4))) float f32x4;

__device__ __forceinline__ f32x4 mfma16(bf8 a, bf8 b, f32x4 c) {
  return __builtin_amdgcn_mfma_f32_16x16x32_bf16(a, b, c, 0, 0, 0);
}
__device__ __forceinline__ unsigned short f2bf(float f) {
  union { float f; unsigned u; } v; v.f = f;
  unsigned r = v.u + 0x7FFF + ((v.u >> 16) & 1);
  return (unsigned short)(r >> 16);
}
__device__ __forceinline__ float bf2f(unsigned short h) {
  union { unsigned u; float f; } v; v.u = ((unsigned)h) << 16;
  return v.f;
}
__device__ __forceinline__ float wave_max(float v) {
  #pragma unroll
  for (int o = 32; o > 0; o >>= 1) v = fmaxf(v, __shfl_xor(v, o));
  return v;
}
__device__ __forceinline__ float wave_sum(float v) {
  #pragma unroll
  for (int o = 32; o > 0; o >>= 1) v += __shfl_xor(v, o);
  return v;
}

// node[b,n,c] = x[b,c,n]; also bf16 copy
__global__ __launch_bounds__(256) void k_trans(const float* __restrict__ x,
    float* __restrict__ node, unsigned short* __restrict__ nodebf) {
  __shared__ float tile[32][33];
  const int b = blockIdx.z;
  const int n0 = blockIdx.x * 32, c0 = blockIdx.y * 32;
  const int tx = threadIdx.x & 31, ty = threadIdx.x >> 5;
  #pragma unroll
  for (int k = 0; k < 4; ++k) {
    int c = c0 + ty + 8 * k;
    tile[ty + 8 * k][tx] = x[((size_t)b * 320 + c) * 1024 + n0 + tx];
  }
  __syncthreads();
  #pragma unroll
  for (int k = 0; k < 4; ++k) {
    int n = n0 + ty + 8 * k;
    float v = tile[tx][ty + 8 * k];
    size_t idx = ((size_t)b * 1024 + n) * 320 + c0 + tx;
    node[idx] = v;
    nodebf[idx] = f2bf(v);
  }
}

__global__ __launch_bounds__(320) void k_svec(const float* __restrict__ da,
    const float* __restrict__ fw, const float* __restrict__ fb, float* __restrict__ sv) {
  __shared__ float ds[64];
  const int b = blockIdx.x, t = threadIdx.x;
  if (t < 64) {
    float a = 0.f;
    #pragma unroll
    for (int i = 0; i < 16; ++i) a += da[b * 1024 + i * 64 + t];
    ds[t] = a;
  }
  __syncthreads();
  if (t < 320) {
    float acc = 16.f * fb[t];
    #pragma unroll
    for (int e = 0; e < 64; ++e) acc = fmaf(ds[e], fw[t * 64 + e], acc);
    sv[b * 320 + t] = acc;
  }
}

// convert weights fp32->bf16 (qk_w | qkv_w | proj_w concatenated)
__global__ void k_wcvt(const float* __restrict__ a, int na,
                       const float* __restrict__ b, int nb,
                       const float* __restrict__ c, int nc,
                       unsigned short* __restrict__ out) {
  int tot = na + nb + nc;
  for (int i = blockIdx.x * blockDim.x + threadIdx.x; i < tot; i += gridDim.x * blockDim.x) {
    float v = (i < na) ? a[i] : ((i < na + nb) ? b[i - na] : c[i - na - nb]);
    out[i] = f2bf(v);
  }
}

__global__ void k_zero(float4* __restrict__ p) {
  p[blockIdx.x * blockDim.x + threadIdx.x] = make_float4(0.f, 0.f, 0.f, 0.f);
}

// MFMA GEMM: C[2048, Ncols] = A[2048,320]bf16 @ W[Ncols,320]bf16^T (+bias)
// mode 0: p0 fp32 [row*320+col]
// mode 1: col<320 -> qe bf16 [B,N,320]; else ke bf16 [B,N,320]
// mode 2: q->p0 [B,H,N,64]bf16; k->p1 [B,H,N,64]bf16; v->p2 [B,H,48,1024]bf16 (transposed)
// mode 3: p0 fp32 [(b*320+col)*1024+n]
__global__ __launch_bounds__(256, 4) void k_mgemm(
    const unsigned short* __restrict__ A, const unsigned short* __restrict__ W,
    const float* __restrict__ bias, void* p0, void* p1, void* p2, int mode) {
  const int t = threadIdx.x, w = t >> 6, lane = t & 63;
  const int q16 = lane >> 4, l16 = lane & 15;
  const int rt = blockIdx.x * 64, jt = blockIdx.y * 64;
  f32x4 acc[4];
  #pragma unroll
  for (int i = 0; i < 4; ++i)
    #pragma unroll
    for (int j = 0; j < 4; ++j) acc[i][j] = 0.f;
  const unsigned short* ap = A + (size_t)(rt + 16 * w + l16) * 320 + q16 * 8;
  const unsigned short* wp = W + (size_t)(jt + l16) * 320 + q16 * 8;
  for (int kc = 0; kc < 10; ++kc) {
    bf8 af = *(const bf8*)(ap + kc * 32);
    #pragma unroll
    for (int ct = 0; ct < 4; ++ct) {
      bf8 bf = *(const bf8*)(wp + (size_t)ct * 16 * 320 + kc * 32);
      acc[ct] = mfma16(af, bf, acc[ct]);
    }
  }
  #pragma unroll
  for (int ct = 0; ct < 4; ++ct) {
    int col = jt + ct * 16 + l16;
    float bv = bias ? bias[col] : 0.f;
    #pragma unroll
    for (int r = 0; r < 4; ++r) {
      int row = rt + 16 * w + q16 * 4 + r;
      int b = row >> 10, n = row & 1023;
      float v = acc[ct][r] + bv;
      if (mode == 0) {
        ((float*)p0)[(size_t)row * 320 + col] = v;
      } else if (mode == 1) {
        if (col < 320) ((unsigned short*)p0)[(size_t)row * 320 + col] = f2bf(v);
        else           ((unsigned short*)p1)[(size_t)row * 320 + col - 320] = f2bf(v);
      } else if (mode == 2) {
        int part = col / 320, rem = col % 320;
        int h = rem / 40, d = rem % 40;
        size_t bh = (size_t)b * 8 + h;
        if (part == 0)      ((unsigned short*)p0)[(bh * 1024 + n) * 64 + d] = f2bf(v);
        else if (part == 1) ((unsigned short*)p1)[(bh * 1024 + n) * 64 + d] = f2bf(v);
        else                ((unsigned short*)p2)[(bh * 48 + d) * 1024 + n] = f2bf(v);
      } else {
        ((float*)p0)[((size_t)b * 320 + col) * 1024 + n] = v;
      }
    }
  }
}

// edge = softmax(qe @ ke^T * EDGE_SCALE)  via MFMA. Block: (b, 16-row tile), 4 waves.
__global__ __launch_bounds__(256, 2) void k_edge2(
    const unsigned short* __restrict__ qe, const unsigned short* __restrict__ ke,
    float* __restrict__ edge) {
  __shared__ float redm[4][16], reds[4][16];
  const int t = threadIdx.x, w = t >> 6, lane = t & 63;
  const int q16 = lane >> 4, l16 = lane & 15;
  const int b = blockIdx.y, n0 = blockIdx.x * 16;
  const unsigned short* qp = qe + ((size_t)b * 1024 + n0 + l16) * 320 + q16 * 8;
  bf8 af[10];
  #pragma unroll
  for (int kc = 0; kc < 10; ++kc) af[kc] = *(const bf8*)(qp + kc * 32);
  f32x4 acc[16];
  #pragma unroll
  for (int i = 0; i < 16; ++i)
    #pragma unroll
    for (int j = 0; j < 4; ++j) acc[i][j] = 0.f;
  const unsigned short* kp = ke + ((size_t)b * 1024 + w * 256 + l16) * 320 + q16 * 8;
  #pragma unroll
  for (int tt = 0; tt < 16; ++tt) {
    const unsigned short* kpt = kp + (size_t)tt * 16 * 320;
    #pragma unroll
    for (int kc = 0; kc < 10; ++kc) {
      bf8 bf = *(const bf8*)(kpt + kc * 32);
      acc[tt] = mfma16(af[kc], bf, acc[tt]);
    }
  }
  float pm[4] = {-3.4e38f, -3.4e38f, -3.4e38f, -3.4e38f};
  #pragma unroll
  for (int tt = 0; tt < 16; ++tt)
    #pragma unroll
    for (int r = 0; r < 4; ++r) {
      acc[tt][r] *= EDGE_SCALE;
      pm[r] = fmaxf(pm[r], acc[tt][r]);
    }
  #pragma unroll
  for (int r = 0; r < 4; ++r)
    #pragma unroll
    for (int o = 1; o <= 8; o <<= 1) pm[r] = fmaxf(pm[r], __shfl_xor(pm[r], o));
  if (l16 == 0) {
    #pragma unroll
    for (int r = 0; r < 4; ++r) redm[w][q16 * 4 + r] = pm[r];
  }
  __syncthreads();
  float m[4], ps[4] = {0.f, 0.f, 0.f, 0.f};
  #pragma unroll
  for (int r = 0; r < 4; ++r)
    m[r] = fmaxf(fmaxf(redm[0][q16 * 4 + r], redm[1][q16 * 4 + r]),
                 fmaxf(redm[2][q16 * 4 + r], redm[3][q16 * 4 + r]));
  #pragma unroll
  for (int tt = 0; tt < 16; ++tt)
    #pragma unroll
    for (int r = 0; r < 4; ++r) ps[r] += __expf(acc[tt][r] - m[r]);
  #pragma unroll
  for (int r = 0; r < 4; ++r)
    #pragma unroll
    for (int o = 1; o <= 8; o <<= 1) ps[r] += __shfl_xor(ps[r], o);
  if (l16 == 0) {
    #pragma unroll
    for (int r = 0; r < 4; ++r) reds[w][q16 * 4 + r] = ps[r];
  }
  __syncthreads();
  float inv[4];
  #pragma unroll
  for (int r = 0; r < 4; ++r)
    inv[r] = 1.f / (reds[0][q16 * 4 + r] + reds[1][q16 * 4 + r] +
                    reds[2][q16 * 4 + r] + reds[3][q16 * 4 + r]);
  float* ep = edge + ((size_t)b * 1024 + n0) * 1024 + w * 256 + l16;
  #pragma unroll
  for (int tt = 0; tt < 16; ++tt)
    #pragma unroll
    for (int r = 0; r < 4; ++r)
      ep[(size_t)(q16 * 4 + r) * 1024 + tt * 16] = __expf(acc[tt][r] - m[r]) * inv[r];
}

// y_bf16 = LN(diag*LN(node)*s + LN(node)) per row; wave = 1 row.
__global__ __launch_bounds__(256) void k_ln(const float* __restrict__ node,
    const float* __restrict__ edge, const float* __restrict__ sv,
    const float* __restrict__ g1, const float* __restrict__ b1,
    const float* __restrict__ g2, const float* __restrict__ b2,
    unsigned short* __restrict__ y) {
  const int w = threadIdx.x >> 6, lane = threadIdx.x & 63;
  const int row = blockIdx.x * 4 + w;
  const int b = row >> 10, n = row & 1023;
  const float* xr = node + (size_t)row * 320;
  float x[5];
  #pragma unroll
  for (int i = 0; i < 5; ++i) x[i] = xr[lane + 64 * i];
  float s = x[0] + x[1] + x[2] + x[3] + x[4];
  float mean = wave_sum(s) * (1.f / 320.f);
  float v = 0.f;
  #pragma unroll
  for (int i = 0; i < 5; ++i) { float d = x[i] - mean; v += d * d; }
  float rstd = rsqrtf(wave_sum(v) * (1.f / 320.f) + LN_EPS);
  float diag = edge[(size_t)row * 1024 + n];
  float n2[5];
  #pragma unroll
  for (int i = 0; i < 5; ++i) {
    int c = lane + 64 * i;
    float nt = (x[i] - mean) * rstd * g1[c] + b1[c];
    n2[i] = diag * nt * sv[b * 320 + c] + nt;
  }
  s = n2[0] + n2[1] + n2[2] + n2[3] + n2[4];
  float mean2 = wave_sum(s) * (1.f / 320.f);
  v = 0.f;
  #pragma unroll
  for (int i = 0; i < 5; ++i) { float d = n2[i] - mean2; v += d * d; }
  float rstd2 = rsqrtf(wave_sum(v) * (1.f / 320.f) + LN_EPS);
  unsigned short* yr = y + (size_t)row * 320;
  #pragma unroll
  for (int i = 0; i < 5; ++i) {
    int c = lane + 64 * i;
    yr[c] = f2bf((n2[i] - mean2) * rstd2 * g2[c] + b2[c]);
  }
}

// Attention scores + AV per (b, h, 16-row tile). MFMA.
// q,k bf16 [B,H,1024,64] (k-dim padded w/ zeros); vt bf16 [B,H,48,1024].
// Writes: thbuf bf16 [B,H,N,1024] = rw_h*(a+attn_logits); att fp32 [B,N,320] = AV.
__global__ __launch_bounds__(256, 3) void k_score(
    const unsigned short* __restrict__ qbf, const unsigned short* __restrict__ kbf,
    const unsigned short* __restrict__ vtb, const float* __restrict__ edge,
    unsigned short* __restrict__ thbuf, float* __restrict__ att,
    const float* __restrict__ ew, const float* __restrict__ eb,
    const float* __restrict__ rw) {
  __shared__ unsigned short a_lds[64][16][20];   // [tile][row][col16 pad20]
  __shared__ float ored[4][3][16][17];
  __shared__ float redm[4][16], reds[4][16];
  const int t = threadIdx.x, w = t >> 6, lane = t & 63;
  const int q16 = lane >> 4, l16 = lane & 15;
  const int n0 = blockIdx.x * 16, h = blockIdx.y, b = blockIdx.z;
  const size_t bh = (size_t)b * 8 + h;
  const unsigned short* qp = qbf + (bh * 1024 + n0 + l16) * 64 + q16 * 8;
  bf8 af0 = *(const bf8*)(qp);
  bf8 af1 = *(const bf8*)(qp + 32);
  f32x4 acc[16];
  #pragma unroll
  for (int i = 0; i < 16; ++i)
    #pragma unroll
    for (int j = 0; j < 4; ++j) acc[i][j] = 0.f;
  const unsigned short* kp = kbf + (bh * 1024 + (size_t)w * 256 + l16) * 64 + q16 * 8;
  #pragma unroll
  for (int tt = 0; tt < 16; ++tt) {
    const unsigned short* kpt = kp + (size_t)tt * 16 * 64;
    bf8 b0 = *(const bf8*)(kpt);
    bf8 b1 = *(const bf8*)(kpt + 32);
    acc[tt] = mfma16(af0, b0, acc[tt]);
    acc[tt] = mfma16(af1, b1, acc[tt]);
  }
  // bias: S = S*scale + edge*ew + eb
  const float ewh = ew[h], ebh = eb[h], rwh = rw[h];
  const float* ep = edge + ((size_t)b * 1024 + n0 + q16 * 4) * 1024 + w * 256 + l16;
  #pragma unroll
  for (int tt = 0; tt < 16; ++tt)
    #pragma unroll
    for (int r = 0; r < 4; ++r) {
      float ev = ep[(size_t)r * 1024 + tt * 16];
      acc[tt][r] = fmaf(acc[tt][r], ATT_SCALE, fmaf(ev, ewh, ebh));
    }
  // block-wide row softmax
  float pm[4] = {-3.4e38f, -3.4e38f, -3.4e38f, -3.4e38f};
  #pragma unroll
  for (int tt = 0; tt < 16; ++tt)
    #pragma unroll
    for (int r = 0; r < 4; ++r) pm[r] = fmaxf(pm[r], acc[tt][r]);
  #pragma unroll
  for (int r = 0; r < 4; ++r)
    #pragma unroll
    for (int o = 1; o <= 8; o <<= 1) pm[r] = fmaxf(pm[r], __shfl_xor(pm[r], o));
  if (l16 == 0) {
    #pragma unroll
    for (int r = 0; r < 4; ++r) redm[w][q16 * 4 + r] = pm[r];
  }
  __syncthreads();
  float m[4], ps[4] = {0.f, 0.f, 0.f, 0.f};
  #pragma unroll
  for (int r = 0; r < 4; ++r)
    m[r] = fmaxf(fmaxf(redm[0][q16 * 4 + r], redm[1][q16 * 4 + r]),
                 fmaxf(redm[2][q16 * 4 + r], redm[3][q16 * 4 + r]));
  #pragma unroll
  for (int tt = 0; tt < 16; ++tt)
    #pragma unroll
    for (int r = 0; r < 4; ++r) ps[r] += __expf(acc[tt][r] - m[r]);
  #pragma unroll
  for (int r = 0; r < 4; ++r)
    #pragma unroll
    for (int o = 1; o <= 8; o <<= 1) ps[r] += __shfl_xor(ps[r], o);
  if (l16 == 0) {
    #pragma unroll
    for (int r = 0; r < 4; ++r) reds[w][q16 * 4 + r] = ps[r];
  }
  __syncthreads();
  float inv[4];
  #pragma unroll
  for (int r = 0; r < 4; ++r)
    inv[r] = 1.f / (reds[0][q16 * 4 + r] + reds[1][q16 * 4 + r] +
                    reds[2][q16 * 4 + r] + reds[3][q16 * 4 + r]);
  // a -> LDS (bf16), tc -> thbuf
  unsigned short* tp = thbuf + (bh * 1024 + n0 + q16 * 4) * 1024 + w * 256 + l16;
  #pragma unroll
  for (int tt = 0; tt < 16; ++tt)
    #pragma unroll
    for (int r = 0; r < 4; ++r) {
      float e = __expf(acc[tt][r] - m[r]);
      float a = e * inv[r];
      a_lds[w * 16 + tt][q16 * 4 + r][l16] = f2bf(a);
      tp[(size_t)r * 1024 + tt * 16] = f2bf(rwh * (a + acc[tt][r]));
    }
  // AV: wave w handles k-cols [256w, 256w+256) -- its own a_lds tiles.
  f32x4 oacc[3];
  #pragma unroll
  for (int i = 0; i < 3; ++i)
    #pragma unroll
    for (int j = 0; j < 4; ++j) oacc[i][j] = 0.f;
  #pragma unroll
  for (int kc8 = 0; kc8 < 8; ++kc8) {
    int kc = w * 8 + kc8;
    int g0 = kc * 32 + q16 * 8;
    const unsigned short* ap2 = &a_lds[g0 >> 4][l16][g0 & 15];
    short4 lo = *(const short4*)(ap2);
    short4 hi = *(const short4*)(ap2 + 4);
    bf8 afv = {lo.x, lo.y, lo.z, lo.w, hi.x, hi.y, hi.z, hi.w};
    const unsigned short* vp = vtb + (bh * 48 + l16) * 1024 + (size_t)kc * 32 + q16 * 8;
    #pragma unroll
    for (int nt = 0; nt < 3; ++nt) {
      bf8 bfv = *(const bf8*)(vp + (size_t)nt * 16 * 1024);
      oacc[nt] = mfma16(afv, bfv, oacc[nt]);
    }
  }
  #pragma unroll
  for (int nt = 0; nt < 3; ++nt)
    #pragma unroll
    for (int r = 0; r < 4; ++r) ored[w][nt][q16 * 4 + r][l16] = oacc[nt][r];
  __syncthreads();
  #pragma unroll
  for (int k = 0; k < 3; ++k) {
    int o = k * 256 + t;
    int nt = o >> 8, row = (o >> 4) & 15, col = o & 15;
    int dim = nt * 16 + col;
    float sum = ored[0][nt][row][col] + ored[1][nt][row][col] +
                ored[2][nt][row][col] + ored[3][nt][row][col];
    if (dim < 40)
      att[((size_t)b * 1024 + n0 + row) * 320 + h * 40 + dim] = sum;
  }
}

// reduce thbuf over h -> t; edge += t; ws-softmax -> wsum; attbf = att + wsum (bf16)
__global__ __launch_bounds__(256) void k_wsum(
    const unsigned short* __restrict__ thbuf, float* __restrict__ edge,
    const float* __restrict__ att, unsigned short* __restrict__ attbf,
    const float* __restrict__ rb) {
  const int w = threadIdx.x >> 6, lane = threadIdx.x & 63;
  const int row = blockIdx.x * 4 + w;
  const int b = row >> 10, n = row & 1023;
  const float rbv = rb[0];
  float tv[16];
  #pragma unroll
  for (int i = 0; i < 16; ++i) tv[i] = rbv;
  #pragma unroll 1
  for (int h = 0; h < 8; ++h) {
    const unsigned short* tph = thbuf + (((size_t)b * 8 + h) * 1024 + n) * 1024 + lane * 4;
    #pragma unroll
    for (int seg = 0; seg < 4; ++seg) {
      ushort4 u = *(const ushort4*)(tph + seg * 256);
      tv[seg * 4 + 0] += bf2f(u.x);
      tv[seg * 4 + 1] += bf2f(u.y);
      tv[seg * 4 + 2] += bf2f(u.z);
      tv[seg * 4 + 3] += bf2f(u.w);
    }
  }
  float4* erp = (float4*)(edge + ((size_t)b * 1024 + n) * 1024) + lane;
  #pragma unroll
  for (int seg = 0; seg < 4; ++seg) {
    float4 e = erp[seg * 64];
    e.x += tv[seg * 4 + 0]; e.y += tv[seg * 4 + 1];
    e.z += tv[seg * 4 + 2]; e.w += tv[seg * 4 + 3];
    erp[seg * 64] = e;
  }
  float mx = -3.4e38f;
  #pragma unroll
  for (int i = 0; i < 16; ++i) mx = fmaxf(mx, tv[i]);
  mx = wave_max(mx);
  float s = 0.f, num = 0.f;
  #pragma unroll
  for (int i = 0; i < 16; ++i) {
    float e = __expf(tv[i] - mx);
    s += e; num += e * tv[i];
  }
  s = wave_sum(s); num = wave_sum(num);
  const float wsum = num / s;
  const float* ar = att + (size_t)row * 320;
  unsigned short* ao = attbf + (size_t)row * 320;
  #pragma unroll
  for (int i = 0; i < 5; ++i) {
    int c = lane + 64 * i;
    ao[c] = f2bf(ar[c] + wsum);
  }
}

extern "C" void kernel_launch(void* const* d_in, const int* in_sizes, int n_in,
                              void* d_out, int out_size, void* d_ws, size_t ws_size,
                              hipStream_t stream) {
  const float* x      = (const float*)d_in[0];
  const float* da     = (const float*)d_in[1];
  const float* qk_w   = (const float*)d_in[2];
  const float* fcp_w  = (const float*)d_in[3];
  const float* fcp_b  = (const float*)d_in[4];
  const float* ln1_g  = (const float*)d_in[5];
  const float* ln1_b  = (const float*)d_in[6];
  const float* gln_g  = (const float*)d_in[7];
  const float* gln_b  = (const float*)d_in[8];
  const float* qkv_w  = (const float*)d_in[9];
  const float* qkv_b  = (const float*)d_in[10];
  const float* proj_w = (const float*)d_in[11];
  const float* proj_b = (const float*)d_in[12];
  const float* exp_w  = (const float*)d_in[13];
  const float* exp_b  = (const float*)d_in[14];
  const float* red_w  = (const float*)d_in[15];
  const float* red_b  = (const float*)d_in[16];
  float* ws = (float*)d_ws;
  // float offsets
  float* node  = ws + 0;                                   // 655360
  unsigned short* ybf   = (unsigned short*)(ws + 655360);  // 327680 fl
  float* attb  = ws + 983040;                              // 655360
  unsigned short* attbf = (unsigned short*)(ws + 1638400); // 327680 fl
  float* edge  = ws + 1966080;                             // 2097152
  float* svec  = ws + 4063232;                             // 640
  unsigned short* nodebf = (unsigned short*)(ws + 4063872);// 327680 fl
  unsigned short* qe   = (unsigned short*)(ws + 4391552);  // 327680 fl
  unsigned short* ke   = (unsigned short*)(ws + 4719232);  // 327680 fl
  unsigned short* qbf  = (unsigned short*)(ws + 5046912);  // 524288 fl
  unsigned short* kbf  = (unsigned short*)(ws + 5571200);  // 524288 fl
  unsigned short* vtb  = (unsigned short*)(ws + 6095488);  // 393216 fl
  unsigned short* wbf  = (unsigned short*)(ws + 6488704);  // 512000 fl
  unsigned short* thbuf= (unsigned short*)(ws + 7000704);  // 8388608 fl
  float* out = (float*)d_out;
  unsigned short* qk_wb   = wbf;
  unsigned short* qkv_wb  = wbf + 204800;
  unsigned short* proj_wb = wbf + 819200;

  hipLaunchKernelGGL(k_trans, dim3(32, 10, 2), dim3(256), 0, stream, x, node, nodebf);
  hipLaunchKernelGGL(k_svec, dim3(2), dim3(320), 0, stream, da, fcp_w, fcp_b, svec);
  hipLaunchKernelGGL(k_wcvt, dim3(512), dim3(256), 0, stream,
                     qk_w, 204800, qkv_w, 614400, proj_w, 204800, wbf);
  hipLaunchKernelGGL(k_mgemm, dim3(32, 10), dim3(256), 0, stream,
                     nodebf, qk_wb, (const float*)nullptr, qe, ke, (void*)nullptr, 1);
  hipLaunchKernelGGL(k_edge2, dim3(64, 2), dim3(256), 0, stream, qe, ke, edge);
  for (int l = 0; l < 2; ++l) {
    hipLaunchKernelGGL(k_ln, dim3(512), dim3(256), 0, stream, node, edge, svec,
                       ln1_g + l * 320, ln1_b + l * 320, gln_g + l * 320, gln_b + l * 320, ybf);
    hipLaunchKernelGGL(k_zero, dim3(1024), dim3(256), 0, stream, (float4*)qbf);
    hipLaunchKernelGGL(k_mgemm, dim3(32, 15), dim3(256), 0, stream,
                       ybf, qkv_wb + (size_t)l * 307200, qkv_b + l * 960, qbf, kbf, vtb, 2);
    hipLaunchKernelGGL(k_score, dim3(64, 8, 2), dim3(256), 0, stream,
                       qbf, kbf, vtb, edge, thbuf, attb,
                       exp_w + l * 8, exp_b + l * 8, red_w + l * 8);
    hipLaunchKernelGGL(k_wsum, dim3(512), dim3(256), 0, stream,
                       thbuf, edge, attb, attbf, red_b + l);
    if (l == 0)
      hipLaunchKernelGGL(k_mgemm, dim3(32, 5), dim3(256), 0, stream,
                         attbf, proj_wb, proj_b, node, (void*)nullptr, (void*)nullptr, 0);
    else
      hipLaunchKernelGGL(k_mgemm, dim3(32, 5), dim3(256), 0, stream,
                         attbf, proj_wb + 102400, proj_b + 320, out,
                         (void*)nullptr, (void*)nullptr, 3);
  }
}

// Round 4
// 293.532 us; speedup vs baseline: 7.8122x; 1.0251x over previous
//
#include <hip/hip_runtime.h>
#include <math.h>

#define EDGE_SCALE 0.17677669529663687f   // 32^-0.5
#define ATT_SCALE  0.15811388300841897f   // 40^-0.5
#define LN_EPS 1e-5f

typedef __attribute__((ext_vector_type(8))) short bf8;
typedef __attribute__((ext_vector_type(4))) float f32x4;

__device__ __forceinline__ f32x4 mfma16(bf8 a, bf8 b, f32x4 c) {
  return __builtin_amdgcn_mfma_f32_16x16x32_bf16(a, b, c, 0, 0, 0);
}
__device__ __forceinline__ unsigned short f2bf(float f) {
  union { float f; unsigned u; } v; v.f = f;
  unsigned r = v.u + 0x7FFF + ((v.u >> 16) & 1);
  return (unsigned short)(r >> 16);
}
__device__ __forceinline__ float bf2f(unsigned short h) {
  union { unsigned u; float f; } v; v.u = ((unsigned)h) << 16;
  return v.f;
}
__device__ __forceinline__ float wave_max(float v) {
  #pragma unroll
  for (int o = 32; o > 0; o >>= 1) v = fmaxf(v, __shfl_xor(v, o));
  return v;
}
__device__ __forceinline__ float wave_sum(float v) {
  #pragma unroll
  for (int o = 32; o > 0; o >>= 1) v += __shfl_xor(v, o);
  return v;
}

// node[b,n,c] = x[b,c,n]; also bf16 copy
__global__ __launch_bounds__(256) void k_trans(const float* __restrict__ x,
    float* __restrict__ node, unsigned short* __restrict__ nodebf) {
  __shared__ float tile[32][33];
  const int b = blockIdx.z;
  const int n0 = blockIdx.x * 32, c0 = blockIdx.y * 32;
  const int tx = threadIdx.x & 31, ty = threadIdx.x >> 5;
  #pragma unroll
  for (int k = 0; k < 4; ++k) {
    int c = c0 + ty + 8 * k;
    tile[ty + 8 * k][tx] = x[((size_t)b * 320 + c) * 1024 + n0 + tx];
  }
  __syncthreads();
  #pragma unroll
  for (int k = 0; k < 4; ++k) {
    int n = n0 + ty + 8 * k;
    float v = tile[tx][ty + 8 * k];
    size_t idx = ((size_t)b * 1024 + n) * 320 + c0 + tx;
    node[idx] = v;
    nodebf[idx] = f2bf(v);
  }
}

__global__ __launch_bounds__(320) void k_svec(const float* __restrict__ da,
    const float* __restrict__ fw, const float* __restrict__ fb, float* __restrict__ sv) {
  __shared__ float ds[64];
  const int b = blockIdx.x, t = threadIdx.x;
  if (t < 64) {
    float a = 0.f;
    #pragma unroll
    for (int i = 0; i < 16; ++i) a += da[b * 1024 + i * 64 + t];
    ds[t] = a;
  }
  __syncthreads();
  if (t < 320) {
    float acc = 16.f * fb[t];
    #pragma unroll
    for (int e = 0; e < 64; ++e) acc = fmaf(ds[e], fw[t * 64 + e], acc);
    sv[b * 320 + t] = acc;
  }
}

// convert weights fp32->bf16 (qk_w | qkv_w | proj_w concatenated)
__global__ void k_wcvt(const float* __restrict__ a, int na,
                       const float* __restrict__ b, int nb,
                       const float* __restrict__ c, int nc,
                       unsigned short* __restrict__ out) {
  int tot = na + nb + nc;
  for (int i = blockIdx.x * blockDim.x + threadIdx.x; i < tot; i += gridDim.x * blockDim.x) {
    float v = (i < na) ? a[i] : ((i < na + nb) ? b[i - na] : c[i - na - nb]);
    out[i] = f2bf(v);
  }
}

// MFMA GEMM: C[2048, Ncols] = A[2048,320]bf16 @ W[Ncols,320]bf16^T (+bias)
// mode 0: p0 fp32 [row*320+col]
// mode 1: col<320 -> qe bf16 [B,N,320]; else ke bf16 [B,N,320]
// mode 2: q->p0 [B,H,N,64]bf16 (d>=40 zero-padded); k->p1 same; v->p2 [B,H,48,1024]bf16
// mode 3: p0 fp32 [(b*320+col)*1024+n] via LDS transpose
__global__ __launch_bounds__(256, 4) void k_mgemm(
    const unsigned short* __restrict__ A, const unsigned short* __restrict__ W,
    const float* __restrict__ bias, void* p0, void* p1, void* p2, int mode) {
  __shared__ float smem[64 * 65];     // mode-3 fp32 tile / mode-2 v-tile (ushort view)
  const int t = threadIdx.x, w = t >> 6, lane = t & 63;
  const int q16 = lane >> 4, l16 = lane & 15;
  const int rt = blockIdx.x * 64, jt = blockIdx.y * 64;
  f32x4 acc[4];
  #pragma unroll
  for (int i = 0; i < 4; ++i)
    #pragma unroll
    for (int j = 0; j < 4; ++j) acc[i][j] = 0.f;
  const unsigned short* ap = A + (size_t)(rt + 16 * w + l16) * 320 + q16 * 8;
  const unsigned short* wp = W + (size_t)(jt + l16) * 320 + q16 * 8;
  for (int kc = 0; kc < 10; ++kc) {
    bf8 af = *(const bf8*)(ap + kc * 32);
    #pragma unroll
    for (int ct = 0; ct < 4; ++ct) {
      bf8 bf = *(const bf8*)(wp + (size_t)ct * 16 * 320 + kc * 32);
      acc[ct] = mfma16(af, bf, acc[ct]);
    }
  }
  if (mode == 0 || mode == 1) {
    #pragma unroll
    for (int ct = 0; ct < 4; ++ct) {
      int col = jt + ct * 16 + l16;
      float bv = bias ? bias[col] : 0.f;
      #pragma unroll
      for (int r = 0; r < 4; ++r) {
        int row = rt + 16 * w + q16 * 4 + r;
        float v = acc[ct][r] + bv;
        if (mode == 0) {
          ((float*)p0)[(size_t)row * 320 + col] = v;
        } else {
          if (col < 320) ((unsigned short*)p0)[(size_t)row * 320 + col] = f2bf(v);
          else           ((unsigned short*)p1)[(size_t)row * 320 + col - 320] = f2bf(v);
        }
      }
    }
  } else if (mode == 2) {
    const int part = jt / 320;       // uniform per block (320 % 64 == 0)
    if (part < 2) {
      unsigned short* dst = (unsigned short*)(part == 0 ? p0 : p1);
      #pragma unroll
      for (int ct = 0; ct < 4; ++ct) {
        int col = jt + ct * 16 + l16;
        float bv = bias[col];
        int rem = col - part * 320;
        int h = rem / 40, d = rem % 40;
        #pragma unroll
        for (int r = 0; r < 4; ++r) {
          int row = rt + 16 * w + q16 * 4 + r;
          int b = row >> 10, n = row & 1023;
          size_t base = (((size_t)b * 8 + h) * 1024 + n) * 64;
          dst[base + d] = f2bf(acc[ct][r] + bv);
          if (d < 24) dst[base + 40 + d] = 0;   // zero the K-pad
        }
      }
    } else {
      // v: stage [col][n] ushort tile, then write [B,H,48,1024] coalesced
      unsigned short* vt_t = (unsigned short*)smem;       // [64][72]
      #pragma unroll
      for (int ct = 0; ct < 4; ++ct) {
        int col = jt + ct * 16 + l16;
        float bv = bias[col];
        #pragma unroll
        for (int r = 0; r < 4; ++r)
          vt_t[(ct * 16 + l16) * 72 + 16 * w + q16 * 4 + r] = f2bf(acc[ct][r] + bv);
      }
      __syncthreads();
      const int cl = t >> 2, seg = t & 3;
      int rem = (jt - 640) + cl;
      int h = rem / 40, d = rem % 40;
      int b = rt >> 10, n = (rt & 1023) + seg * 16;
      const float4* lp = (const float4*)&vt_t[cl * 72 + seg * 16];
      float4 a0 = lp[0], a1 = lp[1];
      float4* gp = (float4*)((unsigned short*)p2 +
                             (((size_t)b * 8 + h) * 48 + d) * 1024 + n);
      gp[0] = a0; gp[1] = a1;
    }
  } else {
    // mode 3: out[(b*320+col)*1024+n] via LDS transpose
    #pragma unroll
    for (int ct = 0; ct < 4; ++ct) {
      int col = jt + ct * 16 + l16;
      float bv = bias[col];
      #pragma unroll
      for (int r = 0; r < 4; ++r)
        smem[(16 * w + q16 * 4 + r) * 65 + ct * 16 + l16] = acc[ct][r] + bv;
    }
    __syncthreads();
    const int cl = t >> 2, seg = t & 3;
    int b = rt >> 10, n = (rt & 1023) + seg * 16;
    float* orow = (float*)p0 + ((size_t)b * 320 + jt + cl) * 1024 + n;
    #pragma unroll
    for (int i2 = 0; i2 < 4; ++i2) {
      float4 vv;
      vv.x = smem[(seg * 16 + i2 * 4 + 0) * 65 + cl];
      vv.y = smem[(seg * 16 + i2 * 4 + 1) * 65 + cl];
      vv.z = smem[(seg * 16 + i2 * 4 + 2) * 65 + cl];
      vv.w = smem[(seg * 16 + i2 * 4 + 3) * 65 + cl];
      ((float4*)orow)[i2] = vv;
    }
  }
}

// S[b,n,m] = (qe[b] @ ke[b]^T) * EDGE_SCALE   (batched MFMA GEMM, 512 blocks)
__global__ __launch_bounds__(256, 4) void k_sgemm(
    const unsigned short* __restrict__ qe, const unsigned short* __restrict__ ke,
    float* __restrict__ S) {
  const int t = threadIdx.x, w = t >> 6, lane = t & 63;
  const int q16 = lane >> 4, l16 = lane & 15;
  const int rt = blockIdx.x * 64, jt = blockIdx.y * 64, b = blockIdx.z;
  const unsigned short* A = qe + (size_t)b * 1024 * 320;
  const unsigned short* W = ke + (size_t)b * 1024 * 320;
  f32x4 acc[4];
  #pragma unroll
  for (int i = 0; i < 4; ++i)
    #pragma unroll
    for (int j = 0; j < 4; ++j) acc[i][j] = 0.f;
  const unsigned short* ap = A + (size_t)(rt + 16 * w + l16) * 320 + q16 * 8;
  const unsigned short* wp = W + (size_t)(jt + l16) * 320 + q16 * 8;
  for (int kc = 0; kc < 10; ++kc) {
    bf8 af = *(const bf8*)(ap + kc * 32);
    #pragma unroll
    for (int ct = 0; ct < 4; ++ct) {
      bf8 bf = *(const bf8*)(wp + (size_t)ct * 16 * 320 + kc * 32);
      acc[ct] = mfma16(af, bf, acc[ct]);
    }
  }
  #pragma unroll
  for (int ct = 0; ct < 4; ++ct)
    #pragma unroll
    for (int r = 0; r < 4; ++r)
      S[((size_t)b * 1024 + rt + 16 * w + q16 * 4 + r) * 1024 + jt + ct * 16 + l16] =
          acc[ct][r] * EDGE_SCALE;
}

// edge[row,:] = softmax(S[row,:])  (wave per row)
__global__ __launch_bounds__(256) void k_smax(const float* __restrict__ S,
                                              float* __restrict__ edge) {
  const int w = threadIdx.x >> 6, lane = threadIdx.x & 63;
  const int row = blockIdx.x * 4 + w;
  const float4* sp = (const float4*)(S + (size_t)row * 1024) + lane;
  float4 v[4];
  #pragma unroll
  for (int i = 0; i < 4; ++i) v[i] = sp[i * 64];
  float mx = -3.4e38f;
  #pragma unroll
  for (int i = 0; i < 4; ++i)
    mx = fmaxf(mx, fmaxf(fmaxf(v[i].x, v[i].y), fmaxf(v[i].z, v[i].w)));
  mx = wave_max(mx);
  float s = 0.f;
  #pragma unroll
  for (int i = 0; i < 4; ++i) {
    v[i].x = __expf(v[i].x - mx); v[i].y = __expf(v[i].y - mx);
    v[i].z = __expf(v[i].z - mx); v[i].w = __expf(v[i].w - mx);
    s += v[i].x + v[i].y + v[i].z + v[i].w;
  }
  s = wave_sum(s);
  float inv = 1.f / s;
  float4* ep = (float4*)(edge + (size_t)row * 1024) + lane;
  #pragma unroll
  for (int i = 0; i < 4; ++i)
    ep[i * 64] = make_float4(v[i].x * inv, v[i].y * inv, v[i].z * inv, v[i].w * inv);
}

// y_bf16 = LN(diag*LN(node)*s + LN(node)) per row; wave = 1 row.
__global__ __launch_bounds__(256) void k_ln(const float* __restrict__ node,
    const float* __restrict__ edge, const float* __restrict__ sv,
    const float* __restrict__ g1, const float* __restrict__ b1,
    const float* __restrict__ g2, const float* __restrict__ b2,
    unsigned short* __restrict__ y) {
  const int w = threadIdx.x >> 6, lane = threadIdx.x & 63;
  const int row = blockIdx.x * 4 + w;
  const int b = row >> 10, n = row & 1023;
  const float* xr = node + (size_t)row * 320;
  float x[5];
  #pragma unroll
  for (int i = 0; i < 5; ++i) x[i] = xr[lane + 64 * i];
  float s = x[0] + x[1] + x[2] + x[3] + x[4];
  float mean = wave_sum(s) * (1.f / 320.f);
  float v = 0.f;
  #pragma unroll
  for (int i = 0; i < 5; ++i) { float d = x[i] - mean; v += d * d; }
  float rstd = rsqrtf(wave_sum(v) * (1.f / 320.f) + LN_EPS);
  float diag = edge[(size_t)row * 1024 + n];
  float n2[5];
  #pragma unroll
  for (int i = 0; i < 5; ++i) {
    int c = lane + 64 * i;
    float nt = (x[i] - mean) * rstd * g1[c] + b1[c];
    n2[i] = diag * nt * sv[b * 320 + c] + nt;
  }
  s = n2[0] + n2[1] + n2[2] + n2[3] + n2[4];
  float mean2 = wave_sum(s) * (1.f / 320.f);
  v = 0.f;
  #pragma unroll
  for (int i = 0; i < 5; ++i) { float d = n2[i] - mean2; v += d * d; }
  float rstd2 = rsqrtf(wave_sum(v) * (1.f / 320.f) + LN_EPS);
  unsigned short* yr = y + (size_t)row * 320;
  #pragma unroll
  for (int i = 0; i < 5; ++i) {
    int c = lane + 64 * i;
    yr[c] = f2bf((n2[i] - mean2) * rstd2 * g2[c] + b2[c]);
  }
}

// Attention scores + AV per (b, h, 16-row tile). MFMA, grouped LDS pipeline.
__global__ __launch_bounds__(256, 4) void k_score(
    const unsigned short* __restrict__ qbf, const unsigned short* __restrict__ kbf,
    const unsigned short* __restrict__ vtb, const float* __restrict__ edge,
    unsigned short* __restrict__ thbuf, float* __restrict__ att,
    const float* __restrict__ ew, const float* __restrict__ eb,
    const float* __restrict__ rw) {
  __shared__ unsigned short a_lds[4][4][16][20];  // [wave][tile-in-group][n-row][m pad]
  __shared__ unsigned short th_lds[4][16][72];    // [wave][n-row][64 m-cols pad72]
  __shared__ float ored[4][3][16][17];
  __shared__ float redm[4][16], reds[4][16];
  const int t = threadIdx.x, w = t >> 6, lane = t & 63;
  const int q16 = lane >> 4, l16 = lane & 15;
  const int n0 = blockIdx.x * 16, h = blockIdx.y, b = blockIdx.z;
  const size_t bh = (size_t)b * 8 + h;
  const unsigned short* qp = qbf + (bh * 1024 + n0 + l16) * 64 + q16 * 8;
  bf8 af0 = *(const bf8*)(qp);
  bf8 af1 = *(const bf8*)(qp + 32);
  f32x4 acc[16];
  #pragma unroll
  for (int i = 0; i < 16; ++i)
    #pragma unroll
    for (int j = 0; j < 4; ++j) acc[i][j] = 0.f;
  const unsigned short* kp = kbf + (bh * 1024 + (size_t)w * 256 + l16) * 64 + q16 * 8;
  #pragma unroll
  for (int tt = 0; tt < 16; ++tt) {
    const unsigned short* kpt = kp + (size_t)tt * 16 * 64;
    bf8 b0 = *(const bf8*)(kpt);
    bf8 b1 = *(const bf8*)(kpt + 32);
    acc[tt] = mfma16(af0, b0, acc[tt]);
    acc[tt] = mfma16(af1, b1, acc[tt]);
  }
  const float ewh = ew[h], ebh = eb[h], rwh = rw[h];
  const float* ep = edge + ((size_t)b * 1024 + n0 + q16 * 4) * 1024 + w * 256 + l16;
  #pragma unroll
  for (int tt = 0; tt < 16; ++tt)
    #pragma unroll
    for (int r = 0; r < 4; ++r) {
      float ev = ep[(size_t)r * 1024 + tt * 16];
      acc[tt][r] = fmaf(acc[tt][r], ATT_SCALE, fmaf(ev, ewh, ebh));
    }
  // block-wide row max
  float pm[4] = {-3.4e38f, -3.4e38f, -3.4e38f, -3.4e38f};
  #pragma unroll
  for (int tt = 0; tt < 16; ++tt)
    #pragma unroll
    for (int r = 0; r < 4; ++r) pm[r] = fmaxf(pm[r], acc[tt][r]);
  #pragma unroll
  for (int r = 0; r < 4; ++r)
    #pragma unroll
    for (int o = 1; o <= 8; o <<= 1) pm[r] = fmaxf(pm[r], __shfl_xor(pm[r], o));
  if (l16 == 0) {
    #pragma unroll
    for (int r = 0; r < 4; ++r) redm[w][q16 * 4 + r] = pm[r];
  }
  __syncthreads();
  float m[4], ps[4] = {0.f, 0.f, 0.f, 0.f};
  #pragma unroll
  for (int r = 0; r < 4; ++r)
    m[r] = fmaxf(fmaxf(redm[0][q16 * 4 + r], redm[1][q16 * 4 + r]),
                 fmaxf(redm[2][q16 * 4 + r], redm[3][q16 * 4 + r]));
  #pragma unroll
  for (int tt = 0; tt < 16; ++tt)
    #pragma unroll
    for (int r = 0; r < 4; ++r) ps[r] += __expf(acc[tt][r] - m[r]);
  #pragma unroll
  for (int r = 0; r < 4; ++r)
    #pragma unroll
    for (int o = 1; o <= 8; o <<= 1) ps[r] += __shfl_xor(ps[r], o);
  if (l16 == 0) {
    #pragma unroll
    for (int r = 0; r < 4; ++r) reds[w][q16 * 4 + r] = ps[r];
  }
  __syncthreads();
  float inv[4];
  #pragma unroll
  for (int r = 0; r < 4; ++r)
    inv[r] = 1.f / (reds[0][q16 * 4 + r] + reds[1][q16 * 4 + r] +
                    reds[2][q16 * 4 + r] + reds[3][q16 * 4 + r]);
  // grouped: a->LDS, th->LDS, AV-MFMA, th writeout (all per-wave private, no barrier)
  f32x4 oacc[3];
  #pragma unroll
  for (int i = 0; i < 3; ++i)
    #pragma unroll
    for (int j = 0; j < 4; ++j) oacc[i][j] = 0.f;
  unsigned short* tbase = thbuf + (bh * 1024 + n0) * 1024 + w * 256;
  const int trow = lane >> 2, tc4 = lane & 3;
  #pragma unroll
  for (int g = 0; g < 4; ++g) {
    #pragma unroll
    for (int ti = 0; ti < 4; ++ti) {
      int tt = g * 4 + ti;
      #pragma unroll
      for (int r = 0; r < 4; ++r) {
        float e = __expf(acc[tt][r] - m[r]);
        float a = e * inv[r];
        a_lds[w][ti][q16 * 4 + r][l16] = f2bf(a);
        th_lds[w][q16 * 4 + r][ti * 16 + l16] = f2bf(rwh * (a + acc[tt][r]));
      }
    }
    #pragma unroll
    for (int kk = 0; kk < 2; ++kk) {
      const unsigned short* ap2 = &a_lds[w][kk * 2 + (q16 >> 1)][l16][(q16 & 1) * 8];
      short4 lo = *(const short4*)(ap2);
      short4 hi = *(const short4*)(ap2 + 4);
      bf8 afv = {lo.x, lo.y, lo.z, lo.w, hi.x, hi.y, hi.z, hi.w};
      int kc = w * 8 + g * 2 + kk;
      const unsigned short* vp = vtb + (bh * 48 + l16) * 1024 + (size_t)kc * 32 + q16 * 8;
      #pragma unroll
      for (int nt = 0; nt < 3; ++nt) {
        bf8 bfv = *(const bf8*)(vp + (size_t)nt * 16 * 1024);
        oacc[nt] = mfma16(afv, bfv, oacc[nt]);
      }
    }
    {
      const float4* lp = (const float4*)&th_lds[w][trow][tc4 * 16];
      float4 v0 = lp[0], v1 = lp[1];
      float4* gp = (float4*)(tbase + (size_t)trow * 1024 + g * 64 + tc4 * 16);
      gp[0] = v0; gp[1] = v1;
    }
  }
  #pragma unroll
  for (int nt = 0; nt < 3; ++nt)
    #pragma unroll
    for (int r = 0; r < 4; ++r) ored[w][nt][q16 * 4 + r][l16] = oacc[nt][r];
  __syncthreads();
  #pragma unroll
  for (int k = 0; k < 3; ++k) {
    int o = k * 256 + t;
    int nt = o >> 8, row = (o >> 4) & 15, col = o & 15;
    int dim = nt * 16 + col;
    float sum = ored[0][nt][row][col] + ored[1][nt][row][col] +
                ored[2][nt][row][col] + ored[3][nt][row][col];
    if (dim < 40)
      att[((size_t)b * 1024 + n0 + row) * 320 + h * 40 + dim] = sum;
  }
}

// reduce thbuf over h -> t; edge += t; ws-softmax -> wsum; attbf = att + wsum (bf16)
__global__ __launch_bounds__(256) void k_wsum(
    const unsigned short* __restrict__ thbuf, float* __restrict__ edge,
    const float* __restrict__ att, unsigned short* __restrict__ attbf,
    const float* __restrict__ rb) {
  const int w = threadIdx.x >> 6, lane = threadIdx.x & 63;
  const int row = blockIdx.x * 4 + w;
  const int b = row >> 10, n = row & 1023;
  const float rbv = rb[0];
  float tv[16];
  #pragma unroll
  for (int i = 0; i < 16; ++i) tv[i] = rbv;
  #pragma unroll 1
  for (int h = 0; h < 8; ++h) {
    const unsigned short* tph = thbuf + (((size_t)b * 8 + h) * 1024 + n) * 1024 + lane * 4;
    #pragma unroll
    for (int seg = 0; seg < 4; ++seg) {
      ushort4 u = *(const ushort4*)(tph + seg * 256);
      tv[seg * 4 + 0] += bf2f(u.x);
      tv[seg * 4 + 1] += bf2f(u.y);
      tv[seg * 4 + 2] += bf2f(u.z);
      tv[seg * 4 + 3] += bf2f(u.w);
    }
  }
  float4* erp = (float4*)(edge + ((size_t)b * 1024 + n) * 1024) + lane;
  #pragma unroll
  for (int seg = 0; seg < 4; ++seg) {
    float4 e = erp[seg * 64];
    e.x += tv[seg * 4 + 0]; e.y += tv[seg * 4 + 1];
    e.z += tv[seg * 4 + 2]; e.w += tv[seg * 4 + 3];
    erp[seg * 64] = e;
  }
  float mx = -3.4e38f;
  #pragma unroll
  for (int i = 0; i < 16; ++i) mx = fmaxf(mx, tv[i]);
  mx = wave_max(mx);
  float s = 0.f, num = 0.f;
  #pragma unroll
  for (int i = 0; i < 16; ++i) {
    float e = __expf(tv[i] - mx);
    s += e; num += e * tv[i];
  }
  s = wave_sum(s); num = wave_sum(num);
  const float wsum = num / s;
  const float* ar = att + (size_t)row * 320;
  unsigned short* ao = attbf + (size_t)row * 320;
  #pragma unroll
  for (int i = 0; i < 5; ++i) {
    int c = lane + 64 * i;
    ao[c] = f2bf(ar[c] + wsum);
  }
}

extern "C" void kernel_launch(void* const* d_in, const int* in_sizes, int n_in,
                              void* d_out, int out_size, void* d_ws, size_t ws_size,
                              hipStream_t stream) {
  const float* x      = (const float*)d_in[0];
  const float* da     = (const float*)d_in[1];
  const float* qk_w   = (const float*)d_in[2];
  const float* fcp_w  = (const float*)d_in[3];
  const float* fcp_b  = (const float*)d_in[4];
  const float* ln1_g  = (const float*)d_in[5];
  const float* ln1_b  = (const float*)d_in[6];
  const float* gln_g  = (const float*)d_in[7];
  const float* gln_b  = (const float*)d_in[8];
  const float* qkv_w  = (const float*)d_in[9];
  const float* qkv_b  = (const float*)d_in[10];
  const float* proj_w = (const float*)d_in[11];
  const float* proj_b = (const float*)d_in[12];
  const float* exp_w  = (const float*)d_in[13];
  const float* exp_b  = (const float*)d_in[14];
  const float* red_w  = (const float*)d_in[15];
  const float* red_b  = (const float*)d_in[16];
  float* ws = (float*)d_ws;
  float* node  = ws + 0;                                   // 655360
  unsigned short* ybf   = (unsigned short*)(ws + 655360);  // 327680 fl
  float* attb  = ws + 983040;                              // 655360
  unsigned short* attbf = (unsigned short*)(ws + 1638400); // 327680 fl
  float* edge  = ws + 1966080;                             // 2097152
  float* svec  = ws + 4063232;                             // 640
  unsigned short* nodebf = (unsigned short*)(ws + 4063872);// 327680 fl
  unsigned short* qe   = (unsigned short*)(ws + 4391552);  // 327680 fl
  unsigned short* ke   = (unsigned short*)(ws + 4719232);  // 327680 fl
  unsigned short* qbf  = (unsigned short*)(ws + 5046912);  // 524288 fl
  unsigned short* kbf  = (unsigned short*)(ws + 5571200);  // 524288 fl
  unsigned short* vtb  = (unsigned short*)(ws + 6095488);  // 393216 fl
  unsigned short* wbf  = (unsigned short*)(ws + 6488704);  // 512000 fl
  unsigned short* thbuf= (unsigned short*)(ws + 7000704);  // 8388608 fl
  float* sbuf = ws + 15389312;                             // 2097152
  float* out = (float*)d_out;
  unsigned short* qk_wb   = wbf;
  unsigned short* qkv_wb  = wbf + 204800;
  unsigned short* proj_wb = wbf + 819200;

  hipLaunchKernelGGL(k_trans, dim3(32, 10, 2), dim3(256), 0, stream, x, node, nodebf);
  hipLaunchKernelGGL(k_svec, dim3(2), dim3(320), 0, stream, da, fcp_w, fcp_b, svec);
  hipLaunchKernelGGL(k_wcvt, dim3(512), dim3(256), 0, stream,
                     qk_w, 204800, qkv_w, 614400, proj_w, 204800, wbf);
  hipLaunchKernelGGL(k_mgemm, dim3(32, 10), dim3(256), 0, stream,
                     nodebf, qk_wb, (const float*)nullptr, qe, ke, (void*)nullptr, 1);
  hipLaunchKernelGGL(k_sgemm, dim3(16, 16, 2), dim3(256), 0, stream, qe, ke, sbuf);
  hipLaunchKernelGGL(k_smax, dim3(512), dim3(256), 0, stream, sbuf, edge);
  for (int l = 0; l < 2; ++l) {
    hipLaunchKernelGGL(k_ln, dim3(512), dim3(256), 0, stream, node, edge, svec,
                       ln1_g + l * 320, ln1_b + l * 320, gln_g + l * 320, gln_b + l * 320, ybf);
    hipLaunchKernelGGL(k_mgemm, dim3(32, 15), dim3(256), 0, stream,
                       ybf, qkv_wb + (size_t)l * 307200, qkv_b + l * 960, qbf, kbf, vtb, 2);
    hipLaunchKernelGGL(k_score, dim3(64, 8, 2), dim3(256), 0, stream,
                       qbf, kbf, vtb, edge, thbuf, attb,
                       exp_w + l * 8, exp_b + l * 8, red_w + l * 8);
    hipLaunchKernelGGL(k_wsum, dim3(512), dim3(256), 0, stream,
                       thbuf, edge, attb, attbf, red_b + l);
    if (l == 0)
      hipLaunchKernelGGL(k_mgemm, dim3(32, 5), dim3(256), 0, stream,
                         attbf, proj_wb, proj_b, node, (void*)nullptr, (void*)nullptr, 0);
    else
      hipLaunchKernelGGL(k_mgemm, dim3(32, 5), dim3(256), 0, stream,
                         attbf, proj_wb + 102400, proj_b + 320, out,
                         (void*)nullptr, (void*)nullptr, 3);
  }
}